// Round 4
// baseline (10207.532 us; speedup 1.0000x reference)
//
#include <hip/hip_runtime.h>
#include <math.h>

#define BB 2
#define DD 768
#define HH 16
#define HDIM 48
#define LL 3
#define NIMG 1024
#define NPAST 16
#define TDEC 20
#define SEQ0 1041
#define SPAD 1064
#define MM (BB*SEQ0)
#define GDEC 48
#define SCALE_QK 0.14433756729740643f

typedef __attribute__((ext_vector_type(4))) float f32x4;
typedef __attribute__((ext_vector_type(8))) short bf16x8;

__device__ __forceinline__ short f2bf(float x) {
  unsigned u = __float_as_uint(x);
  unsigned r = (u + 0x7FFFu + ((u >> 16) & 1u)) >> 16;
  return (short)r;
}
__device__ __forceinline__ float bf2f(short h) {
  return __uint_as_float(((unsigned)(unsigned short)h) << 16);
}

// ---------------- utils ----------------
__device__ __forceinline__ float block_sum256(float v, float* red) {
#pragma unroll
  for (int off = 32; off; off >>= 1) v += __shfl_down(v, off);
  __syncthreads();
  if ((threadIdx.x & 63) == 0) red[threadIdx.x >> 6] = v;
  __syncthreads();
  return red[0] + red[1] + red[2] + red[3];
}

// ---------------- software grid barrier (device scope, generation counter) ----------------
__device__ __forceinline__ void gbar(unsigned* cnt, unsigned* gen, unsigned nb) {
  __syncthreads();
  if (threadIdx.x == 0) {
    __threadfence();  // release prior writes device-wide
    unsigned g = __hip_atomic_load(gen, __ATOMIC_RELAXED, __HIP_MEMORY_SCOPE_AGENT);
    unsigned a = __hip_atomic_fetch_add(cnt, 1u, __ATOMIC_ACQ_REL, __HIP_MEMORY_SCOPE_AGENT);
    if (a == nb - 1u) {
      __hip_atomic_store(cnt, 0u, __ATOMIC_RELAXED, __HIP_MEMORY_SCOPE_AGENT);
      __threadfence();
      __hip_atomic_fetch_add(gen, 1u, __ATOMIC_ACQ_REL, __HIP_MEMORY_SCOPE_AGENT);
    } else {
      while (__hip_atomic_load(gen, __ATOMIC_ACQUIRE, __HIP_MEMORY_SCOPE_AGENT) == g) {
        __builtin_amdgcn_s_sleep(2);
      }
    }
    __threadfence();  // acquire side
  }
  __syncthreads();
}

__global__ void bar_init_kernel(unsigned* bar) {
  for (int i = 0; i < 64; ++i) bar[i] = 0u;
}

// ---------------- build sequence ----------------
__global__ __launch_bounds__(256) void build_img_kernel(
    const float* __restrict__ feats, const float* __restrict__ pe, float* __restrict__ x)
{
  __shared__ float T[64][65];
  int b = blockIdx.y;
  int s0 = blockIdx.x * 64;
  int tid = threadIdx.x;
  int r = tid >> 2;
  int c0 = (tid & 3) << 4;
  for (int d0 = 0; d0 < 768; d0 += 64) {
    const float* fp = feats + ((size_t)b*768 + d0 + r)*1024 + s0 + c0;
#pragma unroll
    for (int i = 0; i < 16; ++i) T[r][c0 + i] = fp[i];
    __syncthreads();
    float* xp = x + ((size_t)(b*SEQ0 + s0 + r))*768 + d0 + c0;
    const float* pp = pe + (size_t)(s0 + r)*768 + d0 + c0;
#pragma unroll
    for (int i = 0; i < 16; ++i) xp[i] = T[c0 + i][r] + pp[i];
    __syncthreads();
  }
}

__global__ __launch_bounds__(256) void build_misc_kernel(
    const float* __restrict__ past, const int* __restrict__ intent,
    const float* __restrict__ int_emb, const float* __restrict__ past_W,
    const float* __restrict__ past_b, const float* __restrict__ te,
    float* __restrict__ x)
{
  int b = blockIdx.y;
  int i = blockIdx.x;  // 0..16
  int tid = threadIdx.x;
  if (i == 0) {
    int idx = intent[b] - 1;
    idx = max(0, min(2, idx));
    for (int d = tid; d < 768; d += 256)
      x[((size_t)(b*SEQ0 + 1024))*768 + d] = int_emb[idx*768 + d];
  } else {
    int pi = i - 1;
    float p0 = past[(b*NPAST + pi)*6 + 0], p1 = past[(b*NPAST + pi)*6 + 1];
    float p2 = past[(b*NPAST + pi)*6 + 2], p3 = past[(b*NPAST + pi)*6 + 3];
    float p4 = past[(b*NPAST + pi)*6 + 4], p5 = past[(b*NPAST + pi)*6 + 5];
    for (int d = tid; d < 768; d += 256) {
      float s = past_b[d] + te[(size_t)pi*768 + d];
      s += p0*past_W[0*768 + d] + p1*past_W[1*768 + d] + p2*past_W[2*768 + d];
      s += p3*past_W[3*768 + d] + p4*past_W[4*768 + d] + p5*past_W[5*768 + d];
      x[((size_t)(b*SEQ0 + 1025 + pi))*768 + d] = s;
    }
  }
}

// ---------------- layernorm (prefill) ----------------
__global__ __launch_bounds__(256) void ln_kernel(
    const float* __restrict__ x, const float* __restrict__ g,
    const float* __restrict__ bta, float* __restrict__ h)
{
  __shared__ float red[4];
  size_t row = blockIdx.x;
  const float* xr = x + row*768;
  float* hr = h + row*768;
  int tid = threadIdx.x;
  float v0 = xr[tid], v1 = xr[tid+256], v2 = xr[tid+512];
  float m = block_sum256(v0+v1+v2, red) * (1.f/768.f);
  float d0 = v0-m, d1 = v1-m, d2 = v2-m;
  float var = block_sum256(d0*d0 + d1*d1 + d2*d2, red) * (1.f/768.f);
  float inv = rsqrtf(var + 1e-5f);
  hr[tid]     = d0*inv*g[tid]     + bta[tid];
  hr[tid+256] = d1*inv*g[tid+256] + bta[tid+256];
  hr[tid+512] = d2*inv*g[tid+512] + bta[tid+512];
}

// ---------------- W convert+transpose: fp32 [K][N] -> bf16 hi/lo [N][K] ----------------
__global__ __launch_bounds__(256) void wconv_kernel(
    const float* __restrict__ W, short* __restrict__ th, short* __restrict__ tl,
    int K, int N)
{
  __shared__ float T[64][68];
  int n0 = blockIdx.x * 64, k0 = blockIdx.y * 64;
  int t = threadIdx.x;
  int r = t >> 2, c0 = (t & 3) * 16;
  const float* src = W + (size_t)(k0 + r)*N + n0 + c0;
#pragma unroll
  for (int j = 0; j < 4; ++j) {
    f32x4 v = *(const f32x4*)(src + 4*j);
    T[r][c0 + 4*j + 0] = v.x; T[r][c0 + 4*j + 1] = v.y;
    T[r][c0 + 4*j + 2] = v.z; T[r][c0 + 4*j + 3] = v.w;
  }
  __syncthreads();
  bf16x8 h0, h1, l0, l1;
#pragma unroll
  for (int i = 0; i < 8; ++i) {
    float x = T[c0 + i][r];
    short hh = f2bf(x);
    h0[i] = hh; l0[i] = f2bf(x - bf2f(hh));
    float y = T[c0 + 8 + i][r];
    short hy = f2bf(y);
    h1[i] = hy; l1[i] = f2bf(y - bf2f(hy));
  }
  size_t dst = (size_t)(n0 + r)*K + k0 + c0;
  *(bf16x8*)(th + dst) = h0;
  *(bf16x8*)(th + dst + 8) = h1;
  *(bf16x8*)(tl + dst) = l0;
  *(bf16x8*)(tl + dst + 8) = l1;
}

// ---------------- MFMA GEMM: C(M,N) = A(M,K) @ W(K,N) + bias ----------------
__global__ __launch_bounds__(256) void gemm_mfma_kernel(
    const float* __restrict__ A, const short* __restrict__ Wh,
    const short* __restrict__ Wl, const float* __restrict__ bias,
    float* __restrict__ C, int M, int N, int K, int mode)
{
  __shared__ short As[2][128][40];   // [hi/lo][m][k]
  __shared__ short Bs[2][128][40];   // [hi/lo][n][k]
  int tid = threadIdx.x;
  int n0 = blockIdx.x * 128, m0 = blockIdx.y * 128;
  int wid = tid >> 6, l = tid & 63;
  int wm = wid >> 1, wn = wid & 1;
  int fr = l & 15, fk = (l >> 4) * 8;
  f32x4 acc[4][4] = {};
  int arow = tid >> 1, akh = (tid & 1) * 16;
  const float* aptr = A + (size_t)(m0 + arow)*K + akh;
  bool aval = (m0 + arow) < M;

  for (int k0 = 0; k0 < K; k0 += 32) {
    {
      float xv[16];
      if (aval) {
        const float* ap = aptr + k0;
#pragma unroll
        for (int j = 0; j < 4; ++j) {
          f32x4 v = *(const f32x4*)(ap + 4*j);
          xv[4*j+0] = v.x; xv[4*j+1] = v.y; xv[4*j+2] = v.z; xv[4*j+3] = v.w;
        }
      } else {
#pragma unroll
        for (int j = 0; j < 16; ++j) xv[j] = 0.f;
      }
      bf16x8 h0, h1, l0, l1;
#pragma unroll
      for (int e = 0; e < 8; ++e) {
        short hh = f2bf(xv[e]);
        h0[e] = hh; l0[e] = f2bf(xv[e] - bf2f(hh));
        short hy = f2bf(xv[8+e]);
        h1[e] = hy; l1[e] = f2bf(xv[8+e] - bf2f(hy));
      }
      *(bf16x8*)&As[0][arow][akh]     = h0;
      *(bf16x8*)&As[0][arow][akh + 8] = h1;
      *(bf16x8*)&As[1][arow][akh]     = l0;
      *(bf16x8*)&As[1][arow][akh + 8] = l1;
    }
#pragma unroll
    for (int cc = 0; cc < 2; ++cc) {
      int c = tid + cc*256;
      int row = c >> 2, woff = (c & 3) * 8;
      size_t src = (size_t)(n0 + row)*K + k0 + woff;
      *(bf16x8*)&Bs[0][row][woff] = *(const bf16x8*)(Wh + src);
      *(bf16x8*)&Bs[1][row][woff] = *(const bf16x8*)(Wl + src);
    }
    __syncthreads();
    bf16x8 af[4][2], bfv[4][2];
#pragma unroll
    for (int i = 0; i < 4; ++i) {
#pragma unroll
      for (int p = 0; p < 2; ++p) {
        af[i][p]  = *(const bf16x8*)&As[p][wm*64 + i*16 + fr][fk];
        bfv[i][p] = *(const bf16x8*)&Bs[p][wn*64 + i*16 + fr][fk];
      }
    }
#pragma unroll
    for (int im = 0; im < 4; ++im) {
#pragma unroll
      for (int in = 0; in < 4; ++in) {
        acc[im][in] = __builtin_amdgcn_mfma_f32_16x16x32_bf16(af[im][0], bfv[in][0], acc[im][in], 0, 0, 0);
        acc[im][in] = __builtin_amdgcn_mfma_f32_16x16x32_bf16(af[im][0], bfv[in][1], acc[im][in], 0, 0, 0);
        acc[im][in] = __builtin_amdgcn_mfma_f32_16x16x32_bf16(af[im][1], bfv[in][0], acc[im][in], 0, 0, 0);
      }
    }
    __syncthreads();
  }
#pragma unroll
  for (int in = 0; in < 4; ++in) {
    int n = n0 + wn*64 + in*16 + (l & 15);
    float bv = bias[n];
#pragma unroll
    for (int im = 0; im < 4; ++im) {
      f32x4 v = acc[im][in];
#pragma unroll
      for (int r = 0; r < 4; ++r) {
        int m = m0 + wm*64 + im*16 + (l >> 4)*4 + r;
        if (m < M) {
          float x = v[r] + bv;
          float* cp = &C[(size_t)m*N + n];
          if (mode == 1) x = fmaxf(x, 0.f);
          if (mode == 2) x += *cp;
          *cp = x;
        }
      }
    }
  }
}

// ---------------- scatter K/V into cache (prefill) ----------------
__global__ __launch_bounds__(256) void scatter_kv_kernel(
    const float* __restrict__ qkv, float* __restrict__ kc, float* __restrict__ vc,
    int S, int spad)
{
  int s = blockIdx.x, b = blockIdx.y;
  const float* row = qkv + ((size_t)b*S + s)*2304;
  int tid = threadIdx.x;
#pragma unroll
  for (int i = 0; i < 3; ++i) {
    int j = tid + i*256;
    int hh = j / 48, hd = j - hh*48;
    size_t dst = ((size_t)(b*16 + hh)*spad + s)*48 + hd;
    kc[dst] = row[768 + j];
    vc[dst] = row[1536 + j];
  }
}

// ---------------- causal flash attention (prefill), 32-row Q tiles ----------------
__global__ __launch_bounds__(256) void attn_prefill_kernel(
    const float* __restrict__ qkv, const float* __restrict__ Kc,
    const float* __restrict__ Vc, float* __restrict__ ctx, int S, int spad)
{
  __shared__ float Qs[32][49];
  __shared__ float Ks[64][49];
  __shared__ float Vs[64][49];
  __shared__ float Ps[32][65];
  __shared__ float mrow[32], lrow[32], resc[32];
  int tid = threadIdx.x;
  int qt = blockIdx.x, h = blockIdx.y, b = blockIdx.z;
  int q0 = qt * 32;
  for (int i = tid; i < 32*48; i += 256) {
    int r = i / 48, d = i - r*48;
    int s = q0 + r;
    Qs[r][d] = (s < S) ? qkv[((size_t)(b*S + s))*2304 + h*48 + d] * SCALE_QK : 0.f;
  }
  if (tid < 32) { mrow[tid] = -INFINITY; lrow[tid] = 0.f; }
  float acc[2][3] = {};
  int pr0 = (tid >> 4) << 1;
  int pc  = tid & 15;
  int sr  = tid & 31;
  int skg = tid >> 5;
  int q_last = min(q0 + 31, S - 1);
  const float* Kb = Kc + (size_t)(b*16 + h)*spad*48;
  const float* Vb = Vc + (size_t)(b*16 + h)*spad*48;
  __syncthreads();
  float qreg[48];
#pragma unroll
  for (int d = 0; d < 48; ++d) qreg[d] = Qs[sr][d];
  for (int k0 = 0; k0 <= q_last; k0 += 64) {
    int kn = min(64, q_last - k0 + 1);
    for (int i = tid; i < 64*48; i += 256) {
      int r = i / 48, d = i - r*48;
      bool ok = r < kn;
      Ks[r][d] = ok ? Kb[(size_t)(k0 + r)*48 + d] : 0.f;
      Vs[r][d] = ok ? Vb[(size_t)(k0 + r)*48 + d] : 0.f;
    }
    __syncthreads();
    {
      int qg = q0 + sr;
#pragma unroll
      for (int jj = 0; jj < 8; ++jj) {
        int k = skg*8 + jj;
        float s = 0.f;
#pragma unroll
        for (int d = 0; d < 48; ++d) s += qreg[d] * Ks[k][d];
        int kg = k0 + k;
        bool valid = (qg < S) && (k < kn) && (kg <= qg);
        Ps[sr][k] = valid ? s : -INFINITY;
      }
    }
    __syncthreads();
    // ---- parallel online softmax: 8 lanes per row, all 256 threads ----
    {
      int r = tid >> 3;            // row 0..31
      int c0 = (tid & 7) * 8;      // col chunk
      float mold = mrow[r];
      float mx = mold;
      float pv[8];
#pragma unroll
      for (int j = 0; j < 8; ++j) { pv[j] = Ps[r][c0 + j]; mx = fmaxf(mx, pv[j]); }
#pragma unroll
      for (int m = 1; m < 8; m <<= 1) mx = fmaxf(mx, __shfl_xor(mx, m));
      float psum = 0.f;
      if (mx > -INFINITY) {
#pragma unroll
        for (int j = 0; j < 8; ++j) {
          float p = __expf(pv[j] - mx);
          Ps[r][c0 + j] = p;
          psum += p;
        }
      } else {
#pragma unroll
        for (int j = 0; j < 8; ++j) Ps[r][c0 + j] = 0.f;
      }
#pragma unroll
      for (int m = 1; m < 8; m <<= 1) psum += __shfl_xor(psum, m);
      if ((tid & 7) == 0) {
        if (mx > -INFINITY) {
          float rs = (mold > -INFINITY) ? __expf(mold - mx) : 0.f;
          lrow[r] = lrow[r]*rs + psum;
          mrow[r] = mx;
          resc[r] = rs;
        } else {
          resc[r] = 1.f;
        }
      }
    }
    __syncthreads();
#pragma unroll
    for (int rr = 0; rr < 2; ++rr) {
      int r = pr0 + rr;
      float f = resc[r];
      float a0 = acc[rr][0]*f, a1 = acc[rr][1]*f, a2 = acc[rr][2]*f;
#pragma unroll 16
      for (int k = 0; k < 64; ++k) {
        float p = Ps[r][k];
        a0 += p * Vs[k][pc*3+0];
        a1 += p * Vs[k][pc*3+1];
        a2 += p * Vs[k][pc*3+2];
      }
      acc[rr][0] = a0; acc[rr][1] = a1; acc[rr][2] = a2;
    }
    __syncthreads();
  }
#pragma unroll
  for (int rr = 0; rr < 2; ++rr) {
    int r = pr0 + rr, s = q0 + r;
    if (s < S) {
      float invl = 1.f / lrow[r];
      float* cp = &ctx[((size_t)(b*S + s))*768 + h*48 + pc*3];
      cp[0] = acc[rr][0]*invl; cp[1] = acc[rr][1]*invl; cp[2] = acc[rr][2]*invl;
    }
  }
}

// ================= persistent decode =================
struct DecParams {
  const float *qkv_W, *qkv_b, *out_W, *out_b;
  const float *ln1_g, *ln1_b, *ln2_g, *ln2_b;
  const float *ff1_W, *ff1_b, *ff2_W, *ff2_b;
  const float *dec1_W, *dec1_b, *dec2_W, *dec2_b;
  const float *pos_W, *pos_b, *time_e;
  const float *xlast;           // xbuf + (SEQ0-1)*DD, stride SEQ0*DD
  float *Kc, *Vc;               // cache base (per-layer stride KVL)
  float *x_tok, *qkv_tok, *ctx_tok, *ff_tok, *hdec;
  float *outp;
  unsigned *bar_cnt, *bar_gen;
};

// decode GEMV phase: vb < N/64; 64 n-outputs per vb, both batches, 4 k-segments.
// mode: 0 store, 1 relu, 2 add, 3 gelu
__device__ void dev_gemv(const float* xin, size_t in_stride,
    const float* W, const float* bias,
    const float* ln_g, const float* ln_b,
    float* out, int K, int N, int mode,
    float* kc, float* vc, int pos)
{
  __shared__ float hs[2][3072];
  __shared__ float part[4][2][64];
  __shared__ float red[4];
  int vb = blockIdx.x;
  if (vb >= (N >> 6)) return;
  int tid = threadIdx.x;
  if (ln_g) {  // K == 768
#pragma unroll
    for (int b = 0; b < 2; ++b) {
      const float* xr = xin + (size_t)b * in_stride;
      float v0 = xr[tid], v1 = xr[tid+256], v2 = xr[tid+512];
      float m = block_sum256(v0+v1+v2, red) * (1.f/768.f);
      float d0 = v0-m, d1 = v1-m, d2 = v2-m;
      float var = block_sum256(d0*d0 + d1*d1 + d2*d2, red) * (1.f/768.f);
      float inv = rsqrtf(var + 1e-5f);
      hs[b][tid]     = d0*inv*ln_g[tid]     + ln_b[tid];
      hs[b][tid+256] = d1*inv*ln_g[tid+256] + ln_b[tid+256];
      hs[b][tid+512] = d2*inv*ln_g[tid+512] + ln_b[tid+512];
    }
  } else {
#pragma unroll
    for (int b = 0; b < 2; ++b) {
      const float* xr = xin + (size_t)b * in_stride;
      for (int k = tid; k < K; k += 256) hs[b][k] = xr[k];
    }
  }
  __syncthreads();
  int lane = tid & 63, seg = tid >> 6;
  int n = vb * 64 + lane;
  int chunk = K >> 2;
  int k0 = seg * chunk;
  const float* wp = W + n;
  float a0 = 0.f, a1 = 0.f;
  for (int k = k0; k < k0 + chunk; k += 8) {
#pragma unroll
    for (int u = 0; u < 8; ++u) {
      float w = wp[(size_t)(k+u)*N];
      a0 += hs[0][k+u] * w;
      a1 += hs[1][k+u] * w;
    }
  }
  part[seg][0][lane] = a0;
  part[seg][1][lane] = a1;
  __syncthreads();
  if (tid < 128) {
    int b = tid >> 6, l = tid & 63;
    int nn = vb * 64 + l;
    float v = bias[nn];
#pragma unroll
    for (int s = 0; s < 4; ++s) v += part[s][b][l];
    if (mode == 1) v = fmaxf(v, 0.f);
    else if (mode == 3) v = 0.5f*v*(1.f + erff(v*0.70710678118654752f));
    if (mode == 2) out[(size_t)b*N + nn] += v;
    else out[(size_t)b*N + nn] = v;
    if (kc) {
      if (nn >= 768 && nn < 1536) {
        int j = nn - 768;
        kc[((size_t)(b*16 + j/48)*SPAD + pos)*48 + (j % 48)] = v;
      } else if (nn >= 1536) {
        int j = nn - 1536;
        vc[((size_t)(b*16 + j/48)*SPAD + pos)*48 + (j % 48)] = v;
      }
    }
  }
}

// decode attention phase: vb < 32 (h = vb&15, b = vb>>4)
__device__ void dev_attn(const float* qkv_tok, const float* Kc, const float* Vc,
                         float* ctx_tok, int S)
{
  __shared__ float qs[48];
  __shared__ float redm[4];
  __shared__ float reds[4];
  __shared__ float aw[4][48];
  int vb = blockIdx.x;
  if (vb >= 32) return;
  int h = vb & 15, b = vb >> 4;
  int tid = threadIdx.x;
  if (tid < 48) qs[tid] = qkv_tok[b*2304 + h*48 + tid] * SCALE_QK;
  __syncthreads();
  const float* Kb = Kc + (size_t)(b*16 + h)*SPAD*48;
  const float* Vb = Vc + (size_t)(b*16 + h)*SPAD*48;
  float ls[5];
  int cnt = 0;
  float lmax = -INFINITY;
  for (int k = tid; k < S; k += 256) {
    const float4* kr = (const float4*)(Kb + (size_t)k*48);
    float s = 0.f;
#pragma unroll
    for (int i = 0; i < 12; ++i) {
      float4 kv = kr[i];
      s += qs[4*i+0]*kv.x + qs[4*i+1]*kv.y + qs[4*i+2]*kv.z + qs[4*i+3]*kv.w;
    }
    ls[cnt++] = s;
    lmax = fmaxf(lmax, s);
  }
#pragma unroll
  for (int off = 32; off; off >>= 1) lmax = fmaxf(lmax, __shfl_down(lmax, off));
  if ((tid & 63) == 0) redm[tid >> 6] = lmax;
  __syncthreads();
  float M = fmaxf(fmaxf(redm[0], redm[1]), fmaxf(redm[2], redm[3]));
  float lsum = 0.f;
  float4 a[12];
#pragma unroll
  for (int i = 0; i < 12; ++i) a[i] = make_float4(0.f, 0.f, 0.f, 0.f);
  cnt = 0;
  for (int k = tid; k < S; k += 256) {
    float p = __expf(ls[cnt++] - M);
    lsum += p;
    const float4* vr = (const float4*)(Vb + (size_t)k*48);
#pragma unroll
    for (int i = 0; i < 12; ++i) {
      float4 vv = vr[i];
      a[i].x += p*vv.x; a[i].y += p*vv.y; a[i].z += p*vv.z; a[i].w += p*vv.w;
    }
  }
  float tot = block_sum256(lsum, reds);
#pragma unroll
  for (int i = 0; i < 12; ++i) {
    float x0 = a[i].x, x1 = a[i].y, x2 = a[i].z, x3 = a[i].w;
#pragma unroll
    for (int off = 32; off; off >>= 1) {
      x0 += __shfl_down(x0, off); x1 += __shfl_down(x1, off);
      x2 += __shfl_down(x2, off); x3 += __shfl_down(x3, off);
    }
    if ((tid & 63) == 0) {
      int w = tid >> 6;
      aw[w][4*i+0] = x0; aw[w][4*i+1] = x1; aw[w][4*i+2] = x2; aw[w][4*i+3] = x3;
    }
  }
  __syncthreads();
  if (tid < 48) {
    float s = aw[0][tid] + aw[1][tid] + aw[2][tid] + aw[3][tid];
    ctx_tok[b*768 + h*48 + tid] = s / tot;
  }
}

// head stage 2 phase: vb == 0 only
__device__ void dev_head2(const DecParams& P, int t, int write_next)
{
  __shared__ float ps[2][2];
  if (blockIdx.x != 0) return;
  int tid = threadIdx.x;
  int w = tid >> 6, lane = tid & 63;
  int b = w >> 1, j = w & 1;
  float partial = 0.f;
  for (int k = lane; k < 768; k += 64) partial += P.hdec[b*768 + k] * P.dec2_W[k*2 + j];
#pragma unroll
  for (int off = 32; off; off >>= 1) partial += __shfl_down(partial, off);
  if (lane == 0) {
    float v = partial + P.dec2_b[j];
    ps[b][j] = v;
    P.outp[(b*TDEC + t)*2 + j] = v;
  }
  __syncthreads();
  if (write_next) {
    for (int i = tid; i < 2*768; i += 256) {
      int b2 = i / 768, d = i - b2*768;
      P.x_tok[i] = ps[b2][0]*P.pos_W[d] + ps[b2][1]*P.pos_W[768 + d]
                 + P.pos_b[d] + P.time_e[(size_t)(NPAST + t)*768 + d];
    }
  }
}

__global__ __launch_bounds__(256) void decode_persistent_kernel(DecParams P)
{
  const unsigned nb = gridDim.x;
  const size_t KVL = (size_t)BB*HH*SPAD*HDIM;
  // ---- t = 0 head (input: last prefill row) ----
  dev_gemv(P.xlast, (size_t)SEQ0*DD, P.dec1_W, P.dec1_b, nullptr, nullptr,
           P.hdec, DD, DD, 3, nullptr, nullptr, 0);
  gbar(P.bar_cnt, P.bar_gen, nb);
  dev_head2(P, 0, 1);
  gbar(P.bar_cnt, P.bar_gen, nb);
  // ---- steps t = 1..19 ----
  for (int t = 1; t < TDEC; ++t) {
    int S = SEQ0 + t;
    int pos = S - 1;
    for (int l = 0; l < LL; ++l) {
      float* kcl = P.Kc + (size_t)l*KVL;
      float* vcl = P.Vc + (size_t)l*KVL;
      dev_gemv(P.x_tok, DD, P.qkv_W + (size_t)l*DD*2304, P.qkv_b + l*2304,
               P.ln1_g + l*DD, P.ln1_b + l*DD, P.qkv_tok, DD, 2304, 0, kcl, vcl, pos);
      gbar(P.bar_cnt, P.bar_gen, nb);
      dev_attn(P.qkv_tok, kcl, vcl, P.ctx_tok, S);
      gbar(P.bar_cnt, P.bar_gen, nb);
      dev_gemv(P.ctx_tok, DD, P.out_W + (size_t)l*DD*DD, P.out_b + l*DD,
               nullptr, nullptr, P.x_tok, DD, DD, 2, nullptr, nullptr, 0);
      gbar(P.bar_cnt, P.bar_gen, nb);
      dev_gemv(P.x_tok, DD, P.ff1_W + (size_t)l*DD*3072, P.ff1_b + l*3072,
               P.ln2_g + l*DD, P.ln2_b + l*DD, P.ff_tok, DD, 3072, 1, nullptr, nullptr, 0);
      gbar(P.bar_cnt, P.bar_gen, nb);
      dev_gemv(P.ff_tok, 3072, P.ff2_W + (size_t)l*3072*DD, P.ff2_b + l*DD,
               nullptr, nullptr, P.x_tok, 3072, DD, 2, nullptr, nullptr, 0);
      gbar(P.bar_cnt, P.bar_gen, nb);
    }
    dev_gemv(P.x_tok, DD, P.dec1_W, P.dec1_b, nullptr, nullptr,
             P.hdec, DD, DD, 3, nullptr, nullptr, 0);
    gbar(P.bar_cnt, P.bar_gen, nb);
    dev_head2(P, t, (t < TDEC - 1) ? 1 : 0);
    gbar(P.bar_cnt, P.bar_gen, nb);
  }
}

// ---------------- host ----------------
extern "C" void kernel_launch(void* const* d_in, const int* in_sizes, int n_in,
                              void* d_out, int out_size, void* d_ws, size_t ws_size,
                              hipStream_t stream) {
  (void)in_sizes; (void)n_in; (void)out_size; (void)ws_size;
  const float* feats   = (const float*)d_in[0];
  const float* past    = (const float*)d_in[1];
  const int*   intent  = (const int*)d_in[2];
  const float* img_pos = (const float*)d_in[3];
  const float* time_e  = (const float*)d_in[4];
  const float* int_emb = (const float*)d_in[5];
  const float* past_W  = (const float*)d_in[6];
  const float* past_b  = (const float*)d_in[7];
  const float* pos_W   = (const float*)d_in[8];
  const float* pos_b   = (const float*)d_in[9];
  const float* ln1_g   = (const float*)d_in[10];
  const float* ln1_b   = (const float*)d_in[11];
  const float* qkv_W   = (const float*)d_in[12];
  const float* qkv_b   = (const float*)d_in[13];
  const float* out_W   = (const float*)d_in[14];
  const float* out_b   = (const float*)d_in[15];
  const float* ln2_g   = (const float*)d_in[16];
  const float* ln2_b   = (const float*)d_in[17];
  const float* ff1_W   = (const float*)d_in[18];
  const float* ff1_b   = (const float*)d_in[19];
  const float* ff2_W   = (const float*)d_in[20];
  const float* ff2_b   = (const float*)d_in[21];
  const float* dec1_W  = (const float*)d_in[22];
  const float* dec1_b  = (const float*)d_in[23];
  const float* dec2_W  = (const float*)d_in[24];
  const float* dec2_b  = (const float*)d_in[25];
  float* outp = (float*)d_out;

  float* ws = (float*)d_ws;
  size_t off = 0;
  float* xbuf = ws + off;   off += (size_t)MM*DD;
  float* hbuf = ws + off;   off += (size_t)MM*DD;
  float* ctxbuf = hbuf;  // alias: h consumed before attention writes ctx
  float* bigbuf = ws + off; off += (size_t)MM*3072;
  float* Kc = ws + off;     off += (size_t)LL*BB*HH*SPAD*HDIM;
  float* Vc = ws + off;     off += (size_t)LL*BB*HH*SPAD*HDIM;
  float* x_tok = ws + off;  off += BB*DD;
  float* hdec = ws + off;   off += BB*DD;
  float* qkv_tok = ws + off; off += BB*2304;
  float* ctx_tok = ws + off; off += BB*DD;
  float* ff_tok = ws + off;  off += BB*3072;
  short* wt_h = (short*)(ws + off); off += (size_t)768*3072/2;
  short* wt_l = (short*)(ws + off); off += (size_t)768*3072/2;
  unsigned* bar = (unsigned*)(ws + off); off += 64;

  const size_t KVL = (size_t)BB*HH*SPAD*HDIM;

  // ---- build initial sequence ----
  build_img_kernel<<<dim3(NIMG/64, BB), 256, 0, stream>>>(feats, img_pos, xbuf);
  build_misc_kernel<<<dim3(17, BB), 256, 0, stream>>>(past, intent, int_emb, past_W, past_b, time_e, xbuf);

  // ---- prefill ----
  const int mtiles = (MM + 127) / 128;  // 17
  for (int l = 0; l < LL; ++l) {
    float* kcl = Kc + (size_t)l*KVL;
    float* vcl = Vc + (size_t)l*KVL;

    ln_kernel<<<MM, 256, 0, stream>>>(xbuf, ln1_g + l*DD, ln1_b + l*DD, hbuf);
    wconv_kernel<<<dim3(2304/64, 768/64), 256, 0, stream>>>(
        qkv_W + (size_t)l*DD*2304, wt_h, wt_l, DD, 2304);
    gemm_mfma_kernel<<<dim3(2304/128, mtiles), 256, 0, stream>>>(
        hbuf, wt_h, wt_l, qkv_b + l*2304, bigbuf, MM, 2304, DD, 0);

    scatter_kv_kernel<<<dim3(SEQ0, BB), 256, 0, stream>>>(bigbuf, kcl, vcl, SEQ0, SPAD);
    attn_prefill_kernel<<<dim3((SEQ0 + 31)/32, HH, BB), 256, 0, stream>>>(
        bigbuf, kcl, vcl, ctxbuf, SEQ0, SPAD);

    wconv_kernel<<<dim3(768/64, 768/64), 256, 0, stream>>>(
        out_W + (size_t)l*DD*DD, wt_h, wt_l, DD, 768);
    gemm_mfma_kernel<<<dim3(768/128, mtiles), 256, 0, stream>>>(
        ctxbuf, wt_h, wt_l, out_b + l*DD, xbuf, MM, 768, DD, 2);

    ln_kernel<<<MM, 256, 0, stream>>>(xbuf, ln2_g + l*DD, ln2_b + l*DD, hbuf);
    wconv_kernel<<<dim3(3072/64, 768/64), 256, 0, stream>>>(
        ff1_W + (size_t)l*DD*3072, wt_h, wt_l, DD, 3072);
    gemm_mfma_kernel<<<dim3(3072/128, mtiles), 256, 0, stream>>>(
        hbuf, wt_h, wt_l, ff1_b + l*3072, bigbuf, MM, 3072, DD, 1);

    wconv_kernel<<<dim3(768/64, 3072/64), 256, 0, stream>>>(
        ff2_W + (size_t)l*3072*DD, wt_h, wt_l, 3072, 768);
    gemm_mfma_kernel<<<dim3(768/128, mtiles), 256, 0, stream>>>(
        bigbuf, wt_h, wt_l, ff2_b + l*DD, xbuf, MM, 768, 3072, 2);
  }

  // ---- persistent decode (t=0 head + 19 incremental steps) ----
  bar_init_kernel<<<1, 1, 0, stream>>>(bar);
  DecParams P;
  P.qkv_W = qkv_W; P.qkv_b = qkv_b; P.out_W = out_W; P.out_b = out_b;
  P.ln1_g = ln1_g; P.ln1_b = ln1_b; P.ln2_g = ln2_g; P.ln2_b = ln2_b;
  P.ff1_W = ff1_W; P.ff1_b = ff1_b; P.ff2_W = ff2_W; P.ff2_b = ff2_b;
  P.dec1_W = dec1_W; P.dec1_b = dec1_b; P.dec2_W = dec2_W; P.dec2_b = dec2_b;
  P.pos_W = pos_W; P.pos_b = pos_b; P.time_e = time_e;
  P.xlast = xbuf + (size_t)(SEQ0 - 1)*DD;
  P.Kc = Kc; P.Vc = Vc;
  P.x_tok = x_tok; P.qkv_tok = qkv_tok; P.ctx_tok = ctx_tok; P.ff_tok = ff_tok;
  P.hdec = hdec; P.outp = outp;
  P.bar_cnt = bar; P.bar_gen = bar + 32;
  decode_persistent_kernel<<<GDEC, 256, 0, stream>>>(P);
}